// Round 7
// baseline (2492.846 us; speedup 1.0000x reference)
//
#include <hip/hip_runtime.h>
#include <stdint.h>

// Problem constants
#define BB   64
#define TT   512
#define DIN  512
#define HH   1024
#define DOUT 512

// 4 batch groups x 16 rows; per group 16 WGs each owning 64 cols; 8 waves/WG
// K-split (128 K each). Layer 1 (WGs 64..127) pipelined behind layer 0.
// FLAGLESS sync: h staged as fp16 pairs in u32 words, bit0/bit16 = step tag;
// consumers poll their own fragment words until every word carries the
// expected tag. No fences, no flags, stores stay in flight (only expcnt-
// guarded so the data VGPR isn't reused before the store reads it).
#define GROUPS        4
#define ROWS          16
#define WGS_PER_GROUP 16
#define NSLICE        64
#define THREADS       512
#define NW            8
#define TAGM          0x00010001u
#define CSTR          20                 // LDS col stride (floats), 16B-aligned
#define PSZ           (NW * 4 * 16 * CSTR)

typedef __attribute__((ext_vector_type(8))) _Float16 half8;     // MFMA A/B frag
typedef __attribute__((ext_vector_type(4))) float f32x4;        // MFMA acc
typedef __attribute__((ext_vector_type(4))) unsigned int u32x4; // 16B payload

union U4H8 { u32x4 u; half8 h; };
union HU { _Float16 h; unsigned short u; };

__device__ __forceinline__ unsigned tag_of(int t) {
  return (unsigned)((((t >> 1) & 1) ^ 1)) * TAGM;   // per-buffer writes alternate
}

// raw barrier: LDS-ordered only, does NOT drain vmcnt (sc1 stores stay in flight)
__device__ __forceinline__ void lds_barrier() {
  asm volatile("s_waitcnt lgkmcnt(0)\n\ts_barrier" ::: "memory");
}

// ---- batched device-scope (sc1) loads: issue all, ONE waitcnt ----
__device__ __forceinline__ void ld4_sc1(u32x4 c[4], const unsigned short* p) {
  asm volatile(
      "global_load_dwordx4 %0, %4, off sc1\n\t"
      "global_load_dwordx4 %1, %4, off offset:64 sc1\n\t"
      "global_load_dwordx4 %2, %4, off offset:128 sc1\n\t"
      "global_load_dwordx4 %3, %4, off offset:192 sc1\n\t"
      "s_waitcnt vmcnt(0)"
      : "=&v"(c[0]), "=&v"(c[1]), "=&v"(c[2]), "=&v"(c[3])
      : "v"(p) : "memory");
}
__device__ __forceinline__ void ld8_sc1(u32x4 c[4], u32x4 d[4],
                                        const unsigned short* pa,
                                        const unsigned short* pb) {
  asm volatile(
      "global_load_dwordx4 %0, %8, off sc1\n\t"
      "global_load_dwordx4 %1, %8, off offset:64 sc1\n\t"
      "global_load_dwordx4 %2, %8, off offset:128 sc1\n\t"
      "global_load_dwordx4 %3, %8, off offset:192 sc1\n\t"
      "global_load_dwordx4 %4, %9, off sc1\n\t"
      "global_load_dwordx4 %5, %9, off offset:64 sc1\n\t"
      "global_load_dwordx4 %6, %9, off offset:128 sc1\n\t"
      "global_load_dwordx4 %7, %9, off offset:192 sc1\n\t"
      "s_waitcnt vmcnt(0)"
      : "=&v"(c[0]), "=&v"(c[1]), "=&v"(c[2]), "=&v"(c[3]),
        "=&v"(d[0]), "=&v"(d[1]), "=&v"(d[2]), "=&v"(d[3])
      : "v"(pa), "v"(pb) : "memory");
}
// sc1 store + expcnt(0): wait until HW has READ the data VGPR (tens of cycles,
// NOT a memory round trip) so the compiler may reuse the register. Round 6
// omitted this -> loop-carried `word` reg overwritten before the store read
// it -> valid-tag stores carrying the NEXT step's value (the 3.1e-2 bug).
__device__ __forceinline__ void st32_sc1(unsigned int* p, unsigned int v) {
  asm volatile("global_store_dword %0, %1, off sc1\n\ts_waitcnt expcnt(0)"
               :: "v"(p), "v"(v) : "memory");
}
// all 16 words carry the expected tag?
__device__ __forceinline__ bool ok4(const u32x4 c[4], unsigned tagw) {
  bool ok = true;
#pragma unroll
  for (int i = 0; i < 4; ++i)
#pragma unroll
    for (int j = 0; j < 4; ++j)
      ok = ok && ((c[i][j] & TAGM) == tagw);
  return ok;
}
__device__ __forceinline__ void poll4(u32x4 c[4], const unsigned short* p,
                                      unsigned tagw) {
  ld4_sc1(c, p);
  while (__ballot(!ok4(c, tagw)) != 0ull) ld4_sc1(c, p);
}

// One RNN layer scan. L0: X = fp32 x (cached loads), state = h1seq slots
// (write-once, tag always 1). L1: X = h1seq[t] (tag 1), state = st ping-pong
// (tag alternates per buffer occupancy). All staging fp16-pair u32 + tag bits.
template<int KIN, bool L0>
__device__ void scan_body(const void* Xv,
                          const float* Wih, const float* Whh,
                          const float* bih, const float* bhh,
                          unsigned short* seq,                  // h1seq (fp16)
                          unsigned short* st0, unsigned short* st1,
                          int g, int s, float* parts)
{
  constexpr int KIT_IN = KIN / (NW * 32);   // L0: 2, L1: 4
  constexpr int KIT_HH = HH  / (NW * 32);   // 4

  const int j0  = s * NSLICE;
  const int r0  = g * ROWS;
  const int tid = threadIdx.x;
  const int w   = tid >> 6;                 // wave 0..7 (K-split)
  const int l   = tid & 63;
  const int lm  = l & 15;                   // A-row / B-col within 16-tile
  const int lq  = l >> 4;                   // k-quad

  // ---- preload weights as fp16 B-frags (fp32 -> fp16 once) ----
  half8 wih_f[KIT_IN][4];
  half8 whh_f[KIT_HH][4];
#pragma unroll
  for (int kit = 0; kit < KIT_IN; ++kit)
#pragma unroll
    for (int nt = 0; nt < 4; ++nt) {
      int n = j0 + nt * 16 + lm;
      int k = w * (KIN / NW) + kit * 32 + lq * 8;
      const float* wp = Wih + (size_t)n * KIN + k;
#pragma unroll
      for (int j = 0; j < 8; ++j) wih_f[kit][nt][j] = (_Float16)wp[j];
    }
#pragma unroll
  for (int kit = 0; kit < KIT_HH; ++kit)
#pragma unroll
    for (int nt = 0; nt < 4; ++nt) {
      int n = j0 + nt * 16 + lm;
      int k = w * (HH / NW) + kit * 32 + lq * 8;
      const float* wp = Whh + (size_t)n * HH + k;
#pragma unroll
      for (int j = 0; j < 8; ++j) whh_f[kit][nt][j] = (_Float16)wp[j];
    }

  // epilogue: thread -> (row = tid&15, 2 contiguous cols at (tid>>4)*2)
  const int erow = tid & 15;
  const int ecg  = tid >> 4;               // 0..31
  float bias2[2];
#pragma unroll
  for (int j = 0; j < 2; ++j) {
    int c = j0 + ecg * 2 + j;
    bias2[j] = bih[c] + bhh[c];
  }

  const int koff = w * (HH / NW) + lq * 8; // this lane's h k-slice base

  for (int t = 0; t < TT; ++t) {
    float* pb = parts + (t & 1) * PSZ;     // double-buffered LDS
    f32x4 acc[4];
#pragma unroll
    for (int nt = 0; nt < 4; ++nt) acc[nt] = (f32x4){0.f, 0.f, 0.f, 0.f};

    if constexpr (L0) {
      // x: plain cached fp32 loads, issued before the self-poll
      const float* xr = (const float*)Xv
          + ((size_t)(r0 + lm) * TT + t) * KIN + w * (KIN / NW) + lq * 8;
      float4 xa[KIT_IN * 2];
#pragma unroll
      for (int kit = 0; kit < KIT_IN; ++kit) {
        xa[2 * kit]     = *(const float4*)(xr + kit * 32);
        xa[2 * kit + 1] = *(const float4*)(xr + kit * 32 + 4);
      }
      u32x4 sc[4];
      if (t > 0)  // self gate: poll h1seq[t-1] words (tag always 1)
        poll4(sc, seq + ((size_t)(r0 + lm) * TT + (t - 1)) * HH + koff, TAGM);

#pragma unroll
      for (int kit = 0; kit < KIT_IN; ++kit) {
        half8 a;
#pragma unroll
        for (int j = 0; j < 4; ++j) {
          a[j]     = (_Float16)(((const float*)&xa[2 * kit])[j]);
          a[4 + j] = (_Float16)(((const float*)&xa[2 * kit + 1])[j]);
        }
#pragma unroll
        for (int nt = 0; nt < 4; ++nt)
          acc[nt] = __builtin_amdgcn_mfma_f32_16x16x32_f16(a, wih_f[kit][nt], acc[nt], 0, 0, 0);
      }
      if (t > 0) {
#pragma unroll
        for (int kit = 0; kit < KIT_HH; ++kit) {
          U4H8 u; u.u = sc[kit];
#pragma unroll
          for (int nt = 0; nt < 4; ++nt)
            acc[nt] = __builtin_amdgcn_mfma_f32_16x16x32_f16(u.h, whh_f[kit][nt], acc[nt], 0, 0, 0);
        }
      }
    } else {
      const unsigned short* px =
          (const unsigned short*)Xv + ((size_t)(r0 + lm) * TT + t) * KIN + koff;
      u32x4 xc[4], sc[4];
      if (t > 0) {
        const unsigned short* ph =
            ((t & 1) ? st0 : st1) + (size_t)(r0 + lm) * HH + koff;  // buf (t-1)&1
        const unsigned tg = tag_of(t - 1);
        ld8_sc1(xc, sc, px, ph);                   // both gates, ONE round trip
        while (__ballot(!ok4(xc, TAGM)) != 0ull) ld4_sc1(xc, px);
        while (__ballot(!ok4(sc, tg))   != 0ull) ld4_sc1(sc, ph);
#pragma unroll
        for (int kit = 0; kit < KIT_IN; ++kit) {
          U4H8 u; u.u = xc[kit];
#pragma unroll
          for (int nt = 0; nt < 4; ++nt)
            acc[nt] = __builtin_amdgcn_mfma_f32_16x16x32_f16(u.h, wih_f[kit][nt], acc[nt], 0, 0, 0);
        }
#pragma unroll
        for (int kit = 0; kit < KIT_HH; ++kit) {
          U4H8 u; u.u = sc[kit];
#pragma unroll
          for (int nt = 0; nt < 4; ++nt)
            acc[nt] = __builtin_amdgcn_mfma_f32_16x16x32_f16(u.h, whh_f[kit][nt], acc[nt], 0, 0, 0);
        }
      } else {
        poll4(xc, px, TAGM);
#pragma unroll
        for (int kit = 0; kit < KIT_IN; ++kit) {
          U4H8 u; u.u = xc[kit];
#pragma unroll
          for (int nt = 0; nt < 4; ++nt)
            acc[nt] = __builtin_amdgcn_mfma_f32_16x16x32_f16(u.h, wih_f[kit][nt], acc[nt], 0, 0, 0);
        }
      }
    }

    // ---- pass1: K-split partials to LDS, vector b128 writes ----
    // C/D layout: col = lane&15, row = (lane>>4)*4 + reg  [verified m89/m91]
    // LDS layout [slot=w*4+nt][col][row], col stride CSTR (16B aligned)
#pragma unroll
    for (int nt = 0; nt < 4; ++nt)
      *(f32x4*)&pb[((w * 4 + nt) * 16 + lm) * CSTR + lq * 4] = acc[nt];
    lds_barrier();   // single barrier/step: `pb` alternates by t&1, so next
                     // step's pass1 writes the other buffer (no reuse hazard)

    // ---- pass2: reduce 8 K-chunks, tanh, fp16-pair store with tag ----
    const unsigned tw = L0 ? TAGM : tag_of(t);
    unsigned int word = 0;
#pragma unroll
    for (int j = 0; j < 2; ++j) {
      int c  = ecg * 2 + j;
      int nt = c >> 4;
      int lc = c & 15;
      float sm = 0.f;
#pragma unroll
      for (int w8 = 0; w8 < NW; ++w8)
        sm += pb[((w8 * 4 + nt) * 16 + lc) * CSTR + erow];
      float u = sm + bias2[j];
      float e = __expf(2.0f * u);               // tanh via exp, inf-safe
      float hv = 1.0f - 2.0f / (e + 1.0f);
      HU cv; cv.h = (_Float16)hv;               // RNE cvt
      word |= (unsigned)cv.u << (16 * j);
    }
    word = (word & ~TAGM) | tw;                 // steal LSBs for the tag

    unsigned short* dst;
    if constexpr (L0)
      dst = seq + ((size_t)(r0 + erow) * TT + t) * HH + j0 + ecg * 2;
    else
      dst = ((t & 1) ? st1 : st0) + (size_t)(r0 + erow) * HH + j0 + ecg * 2;
    st32_sc1((unsigned int*)dst, word);         // in-flight; word self-verifies
  }
}

__global__ __launch_bounds__(THREADS, 1)
void rnn_fused(const float* x,
               const float* Wih0, const float* Whh0, const float* bih0, const float* bhh0,
               const float* Wih1, const float* Whh1, const float* bih1, const float* bhh1,
               unsigned short* h1seq, unsigned short* st0, unsigned short* st1)
{
  __shared__ float parts[2 * PSZ];   // 80 KB, double-buffered by step parity
  const int wg = blockIdx.x;
  if (wg < GROUPS * WGS_PER_GROUP) {
    const int g = wg / WGS_PER_GROUP, s = wg % WGS_PER_GROUP;
    scan_body<DIN, true>(x, Wih0, Whh0, bih0, bhh0, h1seq, nullptr, nullptr,
                         g, s, parts);
  } else {
    const int wg2 = wg - GROUPS * WGS_PER_GROUP;
    const int g = wg2 / WGS_PER_GROUP, s = wg2 % WGS_PER_GROUP;
    scan_body<HH, false>(h1seq, Wih1, Whh1, bih1, bhh1, h1seq, st0, st1,
                         g, s, parts);
  }
}

// clear staging so stale tags can never validate (0xAA poison is tag-0 but
// we don't rely on that)
__global__ void zero4_kernel(u32x4* __restrict__ p, int n4) {
  int i  = blockIdx.x * blockDim.x + threadIdx.x;
  int st = gridDim.x * blockDim.x;
  u32x4 z = (u32x4){0u, 0u, 0u, 0u};
  for (; i < n4; i += st) p[i] = z;
}

// out[m][n] = h2_last[m] . Wfc[n] + bfc[n]; h2 is fp16 pairs (tag bit = LSB noise)
__global__ void fc_kernel(const unsigned int* __restrict__ h2,
                          const float* __restrict__ Wfc,
                          const float* __restrict__ bfc,
                          float* __restrict__ out)
{
  int idx = blockIdx.x * blockDim.x + threadIdx.x;  // 32768 = 64*512
  int m = idx >> 9;
  int n = idx & 511;
  const unsigned int* hp = h2  + (size_t)m * (HH / 2);
  const float*        wp = Wfc + (size_t)n * HH;
  float acc = 0.f;
#pragma unroll 8
  for (int k = 0; k < HH / 2; ++k) {
    unsigned int wv = hp[k];
    HU a, b;
    a.u = (unsigned short)(wv & 0xffffu);
    b.u = (unsigned short)(wv >> 16);
    acc += (float)a.h * wp[2 * k] + (float)b.h * wp[2 * k + 1];
  }
  out[idx] = acc + bfc[n];
}

extern "C" void kernel_launch(void* const* d_in, const int* in_sizes, int n_in,
                              void* d_out, int out_size, void* d_ws, size_t ws_size,
                              hipStream_t stream)
{
  const float* x    = (const float*)d_in[0];
  const float* Wih0 = (const float*)d_in[1];
  const float* Whh0 = (const float*)d_in[2];
  const float* bih0 = (const float*)d_in[3];
  const float* bhh0 = (const float*)d_in[4];
  const float* Wih1 = (const float*)d_in[5];
  const float* Whh1 = (const float*)d_in[6];
  const float* bih1 = (const float*)d_in[7];
  const float* bhh1 = (const float*)d_in[8];
  const float* Wfc  = (const float*)d_in[9];
  const float* bfc  = (const float*)d_in[10];

  // ws: h1seq fp16 [BB][TT][HH] (64MB) | st0,st1 fp16 [BB][HH] (128KB each)
  unsigned char* ws = (unsigned char*)d_ws;
  unsigned short* h1seq = (unsigned short*)ws;
  unsigned short* st0   = (unsigned short*)(ws + (size_t)BB * TT * HH * 2);
  unsigned short* st1   = st0 + (size_t)BB * HH;

  // zero all staging so stale tags can never validate
  size_t zbytes = (size_t)BB * TT * HH * 2 + 2 * (size_t)BB * HH * 2;
  zero4_kernel<<<2048, 256, 0, stream>>>((u32x4*)ws, (int)(zbytes / 16));

  // fused 2-layer pipelined scan: WGs 0..63 = layer 0, 64..127 = layer 1
  rnn_fused<<<2 * GROUPS * WGS_PER_GROUP, THREADS, 0, stream>>>(
      x, Wih0, Whh0, bih0, bhh0, Wih1, Whh1, bih1, bhh1, h1seq, st0, st1);

  // t=511 writes buffer 511&1 = st1 -> final h2 in st1
  fc_kernel<<<(BB * DOUT) / 256, 256, 0, stream>>>(
      (const unsigned int*)st1, Wfc, bfc, (float*)d_out);
}